// Round 1
// baseline (453.521 us; speedup 1.0000x reference)
//
#include <hip/hip_runtime.h>
#include <hip/hip_fp16.h>
#include <cstdint>

// LocalAttention fused kernel, round 6: occupancy push (3 blocks/CU) + Phase-C
// bank-conflict fix.
//
// vs round 5 (163.5us kernel, VALUBusy 37%, Occupancy 21.7%, 3.08M LDS bank
// conflicts): kernel was latency-bound, not issue-bound. Two changes:
//  - LDS 62,464 -> 52,480 B so 3 blocks/CU fit (launch_bounds(256,3)):
//     * Phase-F output s[c,h,j] (f32, 16.9KB) now lives in the per-c slab of
//       s_an (dead there: each wave reads only its own c-rows and its write
//       data depends on every read, so the in-wave WAR is safe; cross-wave
//       separated by the F->G barrier).
//     * s_ts shrinks to 8,704 B (B-partials 8KB / t32 8.7KB / G-partials 8KB
//       time-share it).
//     * s_aq (2KB) overlays s_eat (aq dead after Phase B; energy written in
//       Phase D, two barriers later).
//  - s_q per-head stride padded 16 -> 20 dwords; Phase C reads it as float4.
//    Old layout put 8 broadcast addresses on 2 banks (4-way conflict, ~3.1M
//    cycles = the whole measured SQ_LDS_BANK_CONFLICT). New banks
//    4*(5h+k) mod 32 are all distinct -> conflict-free.
//
// Algebra (exact in real arithmetic):
//   energy[h,n] = sum_j an[n,j] * t[h,j],  t[h,j] = 0.25 * sum_d' q[h,d'] Wk[j,h*16+d']
//     (bk constant over n -> cancels in softmax)
//   ctx[h,d'] = sum_j s[h,j] * Wv[j,h*16+d'] + (sum_n attnm[h,n]) * bv[h,d']
//     with s[h,:] = attnm[h,:] @ an

#define B_ 16
#define C_ 1024
#define N_ 32
#define H_ 8
#define D_ 128
#define G_ 4
#define T_ 256

typedef unsigned short u16;
typedef unsigned int u32;
typedef __fp16 hw2 __attribute__((ext_vector_type(2)));   // matches builtin sigs

__device__ __forceinline__ u32 pkrtz(float a, float b) {
    hw2 r = __builtin_amdgcn_cvt_pkrtz(a, b);
    return __builtin_bit_cast(u32, r);
}
__device__ __forceinline__ float fdot2(u32 a, u32 b, float c) {
#if __has_builtin(__builtin_amdgcn_fdot2)
    return __builtin_amdgcn_fdot2(__builtin_bit_cast(hw2, a),
                                  __builtin_bit_cast(hw2, b), c, false);
#else
    float2 A = __half22float2(__builtin_bit_cast(__half2, a));
    float2 B = __half22float2(__builtin_bit_cast(__half2, b));
    return fmaf(A.y, B.y, fmaf(A.x, B.x, c));
#endif
}
__device__ __forceinline__ __half2 fma2(u32 a, u32 b, __half2 c) {
    return __hfma2(__builtin_bit_cast(__half2, a),
                   __builtin_bit_cast(__half2, b), c);
}
__device__ __forceinline__ float swishf(float x) {
    float s = __builtin_amdgcn_rcpf(1.0f + __expf(-x));
    return x * s;
}

__global__ __launch_bounds__(T_, 3)
void la_kernel(const float* __restrict__ aq_g,  const float* __restrict__ an_g,
               const float* __restrict__ dist_g, const float* __restrict__ mask_g,
               const float* __restrict__ wq_g,  const float* __restrict__ bq_g,
               const float* __restrict__ wk_g,
               const float* __restrict__ wv_g,  const float* __restrict__ bv_g,
               const float* __restrict__ wf_g,  const float* __restrict__ bfb_g,
               float* __restrict__ attn_o, float* __restrict__ ctx_o)
{
    // LDS: 34816(s_an) + 8704(s_ts) + 2560(s_q) + 4224(s_eat) + 512+512+128+512+512
    //    = 52,480 B  -> 3 blocks/CU
    __shared__ __align__(16) u16   s_an[G_ * N_ * 136];   // gated neighbors f16; per-c f32 s-slab after F
    __shared__ __align__(16) u32   s_ts[G_ * H_ * 68];    // B-partials(f32) / t32(f16 pairs) / G-partials(f32)
    __shared__ __align__(16) float s_q[G_][H_ * 20];      // projected query (unscaled), head stride 20
    __shared__ __align__(16) float s_eat[G_][H_][33];     // aq staging (ph0..B) -> energy f32 (D/E) -> am pairs (F)
    __shared__ float s_dist[G_][N_];
    __shared__ float s_mask[G_][N_];
    __shared__ float s_asum[G_][H_];
    __shared__ __align__(16) float s_wf[D_];
    __shared__ __align__(16) float s_bfb[D_];

    const int tid = threadIdx.x;
    const int b   = blockIdx.x >> 8;          // 256 c-groups per b
    const int c0  = (blockIdx.x & 255) << 2;  // G_=4 c's per block

    const int op = tid & 63;                  // output-pair index (od = 2*op)
    const int js = tid >> 6;                  // j-slice index (rows js*32 .. js*32+31)

    // ---- Prefetch Wq slice into registers (overlaps Phase A an-stream) ----
    float2 wq2[32];
    #pragma unroll
    for (int i = 0; i < 32; i++)
        wq2[i] = ((const float2*)(wq_g + (size_t)(js * 32 + i) * D_))[op];

    // ---- Phase 0: stage small tensors ----
    float* s_aqf = (float*)s_eat;             // [c*128+d], first 2048 B of the s_eat slab
    if (tid < D_) {
        s_wf[tid]  = wf_g[tid];
        s_bfb[tid] = bfb_g[tid];
        int c = tid >> 5, n = tid & 31;
        int gi = (b * C_ + c0 + c) * N_ + n;
        s_dist[c][n] = dist_g[gi];
        s_mask[c][n] = mask_g[gi];
    }
    {
        s_aqf[tid] = aq_g[(b * C_ + c0 + (tid >> 7)) * D_ + (tid & 127)];
        int i2 = tid + 256;
        s_aqf[i2] = aq_g[(b * C_ + c0 + (i2 >> 7)) * D_ + (i2 & 127)];
    }
    __syncthreads();

    // ---- Phase A: stream + swish-gate atom_neighbor -> s_an (f16 pairs) ----
    {
        const float4* gan = (const float4*)(an_g + (size_t)(b * C_ + c0) * N_ * D_);
        #pragma unroll
        for (int k = 0; k < 16; k++) {
            int ci = k * T_ + tid;                  // float4 chunk index, 4096 total
            float4 v = gan[ci];
            int d4 = ci & 31, n = (ci >> 5) & 31, c = ci >> 10;
            float dist = s_dist[c][n];
            int d0 = d4 << 2;
            float4 wf = *(const float4*)&s_wf[d0];
            float4 bb = *(const float4*)&s_bfb[d0];
            float g0 = swishf(fmaf(dist, wf.x, bb.x));
            float g1 = swishf(fmaf(dist, wf.y, bb.y));
            float g2 = swishf(fmaf(dist, wf.z, bb.z));
            float g3 = swishf(fmaf(dist, wf.w, bb.w));
            u32 o0 = pkrtz(v.x * g0, v.y * g1);
            u32 o1 = pkrtz(v.z * g2, v.w * g3);
            *(uint2*)(s_an + (c * N_ + n) * 136 + d0) = make_uint2(o0, o1);
        }
    }

    // ---- Phase B: q partials — thread (op,js) covers j in [js*32, js*32+32) ----
    {
        float acc0[G_], acc1[G_];
        #pragma unroll
        for (int c = 0; c < G_; c++) { acc0[c] = 0.f; acc1[c] = 0.f; }
        #pragma unroll
        for (int i4 = 0; i4 < 8; i4++) {
            #pragma unroll
            for (int c = 0; c < G_; c++) {
                float4 a4 = *(const float4*)&s_aqf[c * D_ + js * 32 + i4 * 4];
                float2 w0 = wq2[i4 * 4], w1 = wq2[i4 * 4 + 1];
                float2 w2 = wq2[i4 * 4 + 2], w3 = wq2[i4 * 4 + 3];
                acc0[c] = fmaf(a4.x, w0.x, acc0[c]); acc1[c] = fmaf(a4.x, w0.y, acc1[c]);
                acc0[c] = fmaf(a4.y, w1.x, acc0[c]); acc1[c] = fmaf(a4.y, w1.y, acc1[c]);
                acc0[c] = fmaf(a4.z, w2.x, acc0[c]); acc1[c] = fmaf(a4.z, w2.y, acc1[c]);
                acc0[c] = fmaf(a4.w, w3.x, acc0[c]); acc1[c] = fmaf(a4.w, w3.y, acc1[c]);
            }
        }
        float* s_part = (float*)s_ts;   // [js][c][128] scratch, 8 KB
        #pragma unroll
        for (int c = 0; c < G_; c++) {
            *(float2*)&s_part[(js * G_ + c) * D_ + 2 * op] = make_float2(acc0[c], acc1[c]);
        }
    }
    __syncthreads();

    // ---- Phase B2: reduce partials -> s_q (head stride 20) ----
    {
        const float* s_part = (const float*)s_ts;
        #pragma unroll
        for (int r = 0; r < 2; r++) {
            int lin = r * 256 + tid;
            int c = lin >> 7, od = lin & 127;
            float sum = s_part[(0 * G_ + c) * D_ + od] + s_part[(1 * G_ + c) * D_ + od]
                      + s_part[(2 * G_ + c) * D_ + od] + s_part[(3 * G_ + c) * D_ + od];
            s_q[c][(od >> 4) * 20 + (od & 15)] = sum + bq_g[od];
        }
    }
    __syncthreads();

    // ---- Prefetch Wv slice (latency hidden behind C/D/E/F) ----
    float2 wv2[32];
    #pragma unroll
    for (int i = 0; i < 32; i++)
        wv2[i] = ((const float2*)(wv_g + (size_t)(js * 32 + i) * D_))[op];

    // ---- Phase C: t[c,h,j] = 0.25*sum_d' q*Wk, packed f16 pairs into t32 ----
    // thread (h, jb) owns j in {2jb, 2jb+1, 64+2jb, 64+2jb+1}
    {
        u32* t32 = s_ts;                   // [c*8+h][68] u32 (f16 pairs), 8.7 KB
        int h = tid & 7, jb = tid >> 3;    // jb in 0..31
        float wk[4][16];
        #pragma unroll
        for (int jj = 0; jj < 4; jj++) {
            int j = 2 * jb + (jj & 1) + (jj >> 1) * 64;
            const float4* pk = (const float4*)(wk_g + j * D_ + h * 16);
            float4 k0 = pk[0], k1 = pk[1], k2 = pk[2], k3 = pk[3];
            wk[jj][0]  = k0.x; wk[jj][1]  = k0.y; wk[jj][2]  = k0.z; wk[jj][3]  = k0.w;
            wk[jj][4]  = k1.x; wk[jj][5]  = k1.y; wk[jj][6]  = k1.z; wk[jj][7]  = k1.w;
            wk[jj][8]  = k2.x; wk[jj][9]  = k2.y; wk[jj][10] = k2.z; wk[jj][11] = k2.w;
            wk[jj][12] = k3.x; wk[jj][13] = k3.y; wk[jj][14] = k3.z; wk[jj][15] = k3.w;
        }
        #pragma unroll
        for (int c = 0; c < G_; c++) {
            const float4* pq = (const float4*)&s_q[c][h * 20];   // 80B base: 16B aligned
            float4 q0 = pq[0], q1 = pq[1], q2 = pq[2], q3 = pq[3];
            float qv[16] = { q0.x, q0.y, q0.z, q0.w, q1.x, q1.y, q1.z, q1.w,
                             q2.x, q2.y, q2.z, q2.w, q3.x, q3.y, q3.z, q3.w };
            float acc[4];
            #pragma unroll
            for (int jj = 0; jj < 4; jj++) {
                float a = 0.f;
                #pragma unroll
                for (int d = 0; d < 16; d++) a = fmaf(qv[d], wk[jj][d], a);
                acc[jj] = a * 0.25f;
            }
            t32[(c * 8 + h) * 68 + jb]      = pkrtz(acc[0], acc[1]);  // pair jb    (j=2jb,2jb+1)
            t32[(c * 8 + h) * 68 + 32 + jb] = pkrtz(acc[2], acc[3]);  // pair jb+32 (j=64+2jb,..)
        }
    }
    __syncthreads();

    // ---- Phase D: energy via v_dot2_f32_f16, fp32 accumulate ----
    {
        const u32* t32 = s_ts;
        int c = tid >> 6, h = (tid >> 3) & 7, n0 = tid & 7;
        const uint4* trow = (const uint4*)(t32 + (c * 8 + h) * 68);
        float acc[4] = {0.f, 0.f, 0.f, 0.f};
        #pragma unroll
        for (int jc = 0; jc < 16; jc++) {
            uint4 t4 = trow[jc];               // 8 f16 = j 8jc..8jc+7
            #pragma unroll
            for (int r = 0; r < 4; r++) {
                int n = n0 + r * 8;
                uint4 a4 = *(const uint4*)(s_an + (c * N_ + n) * 136 + jc * 8);
                float s = acc[r];
                s = fdot2(a4.x, t4.x, s);
                s = fdot2(a4.y, t4.y, s);
                s = fdot2(a4.z, t4.z, s);
                s = fdot2(a4.w, t4.w, s);
                acc[r] = s;
            }
        }
        #pragma unroll
        for (int r = 0; r < 4; r++) {
            int n = n0 + r * 8;
            float mk = s_mask[c][n];
            s_eat[c][h][n] = acc[r] + (1.0f - mk) * (-1.0e9f);
        }
    }
    __syncthreads();

    // ---- Phase E: softmax; write attn to global; store (am,am) f16 pairs ----
    if (tid < G_ * H_) {
        int c = tid >> 3, h = tid & 7;
        float e[N_];
        float m = -3.0e38f;
        #pragma unroll
        for (int n = 0; n < N_; n++) { e[n] = s_eat[c][h][n]; m = fmaxf(m, e[n]); }
        float sum = 0.f;
        #pragma unroll
        for (int n = 0; n < N_; n++) { float p = __expf(e[n] - m); e[n] = p; sum += p; }
        float inv = 1.0f / sum;
        u32* ampk = (u32*)&s_eat[c][h][0];
        float asum = 0.f;
        size_t off = ((size_t)(b * H_ + h) * C_ + (c0 + c)) * N_;
        #pragma unroll
        for (int n4 = 0; n4 < 8; n4++) {
            float4 w;
            w.x = e[n4 * 4]     * inv;
            w.y = e[n4 * 4 + 1] * inv;
            w.z = e[n4 * 4 + 2] * inv;
            w.w = e[n4 * 4 + 3] * inv;
            *(float4*)(attn_o + off + n4 * 4) = w;
            float am0 = w.x * s_mask[c][n4 * 4];
            float am1 = w.y * s_mask[c][n4 * 4 + 1];
            float am2 = w.z * s_mask[c][n4 * 4 + 2];
            float am3 = w.w * s_mask[c][n4 * 4 + 3];
            asum += am0 + am1 + am2 + am3;
            ampk[n4 * 4]     = pkrtz(am0, am0);
            ampk[n4 * 4 + 1] = pkrtz(am1, am1);
            ampk[n4 * 4 + 2] = pkrtz(am2, am2);
            ampk[n4 * 4 + 3] = pkrtz(am3, am3);
        }
        s_asum[c][h] = asum;
    }
    __syncthreads();

    // ---- Phase F: s[c,h,j] = sum_n am*an via v_pk_fma_f16 (f16x2 acc) ----
    // Output s (f32) goes into this c's slab of s_an: each wave reads only its
    // own c-rows and the write data depends on every read -> safe WAR in-wave;
    // other waves never touch this slab.
    {
        int c = tid >> 6, h = (tid >> 3) & 7, jg = tid & 7;
        const u32* ampk = (const u32*)&s_eat[c][h][0];
        __half2 acc2[8];
        #pragma unroll
        for (int i = 0; i < 8; i++) acc2[i] = __float2half2_rn(0.f);
        #pragma unroll 4
        for (int n = 0; n < N_; n++) {
            u32 am2 = ampk[n];
            const uint4* arow = (const uint4*)(s_an + (c * N_ + n) * 136 + jg * 16);
            uint4 a0 = arow[0], a1 = arow[1];
            acc2[0] = fma2(a0.x, am2, acc2[0]);
            acc2[1] = fma2(a0.y, am2, acc2[1]);
            acc2[2] = fma2(a0.z, am2, acc2[2]);
            acc2[3] = fma2(a0.w, am2, acc2[3]);
            acc2[4] = fma2(a1.x, am2, acc2[4]);
            acc2[5] = fma2(a1.y, am2, acc2[5]);
            acc2[6] = fma2(a1.z, am2, acc2[6]);
            acc2[7] = fma2(a1.w, am2, acc2[7]);
        }
        float* srow = (float*)(s_an + c * (N_ * 136)) + h * 132 + jg * 16;
        #pragma unroll
        for (int p = 0; p < 4; p++) {
            float2 lo = __half22float2(acc2[p * 2]);
            float2 hi = __half22float2(acc2[p * 2 + 1]);
            *(float4*)(srow + p * 4) = make_float4(lo.x, lo.y, hi.x, hi.y);
        }
    }
    __syncthreads();

    // ---- Phase G: ctx partials — thread (op,js), Wv read once per block ----
    {
        int h = op >> 3;                  // od = 2*op -> head = od/16
        float acc0[G_], acc1[G_];
        #pragma unroll
        for (int c = 0; c < G_; c++) { acc0[c] = 0.f; acc1[c] = 0.f; }
        #pragma unroll
        for (int i4 = 0; i4 < 8; i4++) {
            #pragma unroll
            for (int c = 0; c < G_; c++) {
                const float* sc_ = (const float*)(s_an + c * (N_ * 136));
                float4 s4 = *(const float4*)&sc_[h * 132 + js * 32 + i4 * 4];
                float2 w0 = wv2[i4 * 4], w1 = wv2[i4 * 4 + 1];
                float2 w2 = wv2[i4 * 4 + 2], w3 = wv2[i4 * 4 + 3];
                acc0[c] = fmaf(s4.x, w0.x, acc0[c]); acc1[c] = fmaf(s4.x, w0.y, acc1[c]);
                acc0[c] = fmaf(s4.y, w1.x, acc0[c]); acc1[c] = fmaf(s4.y, w1.y, acc1[c]);
                acc0[c] = fmaf(s4.z, w2.x, acc0[c]); acc1[c] = fmaf(s4.z, w2.y, acc1[c]);
                acc0[c] = fmaf(s4.w, w3.x, acc0[c]); acc1[c] = fmaf(s4.w, w3.y, acc1[c]);
            }
        }
        float* s_gp = (float*)s_ts;       // 8 KB scratch, t32 dead after D
        #pragma unroll
        for (int c = 0; c < G_; c++) {
            *(float2*)&s_gp[(js * G_ + c) * D_ + 2 * op] = make_float2(acc0[c], acc1[c]);
        }
    }
    __syncthreads();

    // ---- Phase G2: reduce partials + bias + residual -> ctx ----
    {
        const float* s_gp = (const float*)s_ts;
        #pragma unroll
        for (int r = 0; r < 2; r++) {
            int lin = r * 256 + tid;
            int c = lin >> 7, od = lin & 127;
            int h = od >> 4;
            float sum = s_gp[(0 * G_ + c) * D_ + od] + s_gp[(1 * G_ + c) * D_ + od]
                      + s_gp[(2 * G_ + c) * D_ + od] + s_gp[(3 * G_ + c) * D_ + od];
            float r0 = sum + s_asum[c][h] * bv_g[od] + s_q[c][h * 20 + (od & 15)];
            ctx_o[((size_t)(b * C_ + c0 + c)) * D_ + od] = r0;
        }
    }
}

extern "C" void kernel_launch(void* const* d_in, const int* in_sizes, int n_in,
                              void* d_out, int out_size, void* d_ws, size_t ws_size,
                              hipStream_t stream) {
    const float* aq   = (const float*)d_in[0];
    const float* an   = (const float*)d_in[1];
    const float* dist = (const float*)d_in[2];
    const float* mask = (const float*)d_in[3];
    const float* wq   = (const float*)d_in[4];
    const float* bq   = (const float*)d_in[5];
    const float* wk   = (const float*)d_in[6];
    // d_in[7] = bk: constant over n -> cancels exactly in softmax.
    const float* wv   = (const float*)d_in[8];
    const float* bv   = (const float*)d_in[9];
    const float* wf   = (const float*)d_in[10];
    const float* bfb  = (const float*)d_in[11];

    float* attn_o = (float*)d_out;
    float* ctx_o  = attn_o + (size_t)B_ * H_ * C_ * N_;

    dim3 grid(B_ * C_ / G_), block(T_);
    hipLaunchKernelGGL(la_kernel, grid, block, 0, stream,
                       aq, an, dist, mask, wq, bq, wk, wv, bv, wf, bfb,
                       attn_o, ctx_o);
}

// Round 2
// 444.676 us; speedup vs baseline: 1.0199x; 1.0199x over previous
//
#include <hip/hip_runtime.h>
#include <hip/hip_fp16.h>
#include <cstdint>

// LocalAttention fused kernel, round 7: de-spill Phase C.
//
// Round-6 post-mortem (177us, WRITE_SIZE 90MB vs 25MB of real output):
//   float qv[16] = {q0.x, ...} braced-init from float4 components failed SROA
//   -> 16-dword scratch array per thread (64B/thread == the measured +65MB
//   HBM write). VGPR dropped 88->84 (array left the RF). Scratch latency on
//   the Phase-C critical path negated the 3-blocks/CU occupancy win.
// Fix: no qv array at all — fma chain consumes q0..q3 components directly
//   (all compile-time indices). wk[4][16] kept (register-resident in r5).
// Round-6 structural changes retained:
//  - LDS 52,480 B -> 3 blocks/CU (launch_bounds(256,3)):
//     * Phase-F output s[c,h,j] (f32) lives in the per-c slab of s_an
//     * s_ts 8,704 B time-shared (B-partials / t32 / G-partials)
//     * s_aq overlays s_eat (dead after Phase B)
//  - s_q head stride 20 dwords: Phase-C q broadcast reads hit 8 distinct
//    banks (was 4-way conflict on 2 banks = the bulk of r5's 3.1M conflicts)
//
// Algebra (exact in real arithmetic):
//   energy[h,n] = sum_j an[n,j] * t[h,j],  t[h,j] = 0.25 * sum_d' q[h,d'] Wk[j,h*16+d']
//     (bk constant over n -> cancels in softmax)
//   ctx[h,d'] = sum_j s[h,j] * Wv[j,h*16+d'] + (sum_n attnm[h,n]) * bv[h,d']
//     with s[h,:] = attnm[h,:] @ an

#define B_ 16
#define C_ 1024
#define N_ 32
#define H_ 8
#define D_ 128
#define G_ 4
#define T_ 256

typedef unsigned short u16;
typedef unsigned int u32;
typedef __fp16 hw2 __attribute__((ext_vector_type(2)));   // matches builtin sigs

__device__ __forceinline__ u32 pkrtz(float a, float b) {
    hw2 r = __builtin_amdgcn_cvt_pkrtz(a, b);
    return __builtin_bit_cast(u32, r);
}
__device__ __forceinline__ float fdot2(u32 a, u32 b, float c) {
#if __has_builtin(__builtin_amdgcn_fdot2)
    return __builtin_amdgcn_fdot2(__builtin_bit_cast(hw2, a),
                                  __builtin_bit_cast(hw2, b), c, false);
#else
    float2 A = __half22float2(__builtin_bit_cast(__half2, a));
    float2 B = __half22float2(__builtin_bit_cast(__half2, b));
    return fmaf(A.y, B.y, fmaf(A.x, B.x, c));
#endif
}
__device__ __forceinline__ __half2 fma2(u32 a, u32 b, __half2 c) {
    return __hfma2(__builtin_bit_cast(__half2, a),
                   __builtin_bit_cast(__half2, b), c);
}
__device__ __forceinline__ float swishf(float x) {
    float s = __builtin_amdgcn_rcpf(1.0f + __expf(-x));
    return x * s;
}

__global__ __launch_bounds__(T_, 3)
void la_kernel(const float* __restrict__ aq_g,  const float* __restrict__ an_g,
               const float* __restrict__ dist_g, const float* __restrict__ mask_g,
               const float* __restrict__ wq_g,  const float* __restrict__ bq_g,
               const float* __restrict__ wk_g,
               const float* __restrict__ wv_g,  const float* __restrict__ bv_g,
               const float* __restrict__ wf_g,  const float* __restrict__ bfb_g,
               float* __restrict__ attn_o, float* __restrict__ ctx_o)
{
    // LDS: 34816(s_an) + 8704(s_ts) + 2560(s_q) + 4224(s_eat) + 512+512+128+512+512
    //    = 52,480 B  -> 3 blocks/CU
    __shared__ __align__(16) u16   s_an[G_ * N_ * 136];   // gated neighbors f16; per-c f32 s-slab after F
    __shared__ __align__(16) u32   s_ts[G_ * H_ * 68];    // B-partials(f32) / t32(f16 pairs) / G-partials(f32)
    __shared__ __align__(16) float s_q[G_][H_ * 20];      // projected query (unscaled), head stride 20
    __shared__ __align__(16) float s_eat[G_][H_][33];     // aq staging (ph0..B) -> energy f32 (D/E) -> am pairs (F)
    __shared__ float s_dist[G_][N_];
    __shared__ float s_mask[G_][N_];
    __shared__ float s_asum[G_][H_];
    __shared__ __align__(16) float s_wf[D_];
    __shared__ __align__(16) float s_bfb[D_];

    const int tid = threadIdx.x;
    const int b   = blockIdx.x >> 8;          // 256 c-groups per b
    const int c0  = (blockIdx.x & 255) << 2;  // G_=4 c's per block

    const int op = tid & 63;                  // output-pair index (od = 2*op)
    const int js = tid >> 6;                  // j-slice index (rows js*32 .. js*32+31)

    // ---- Prefetch Wq slice into registers (overlaps Phase A an-stream) ----
    float2 wq2[32];
    #pragma unroll
    for (int i = 0; i < 32; i++)
        wq2[i] = ((const float2*)(wq_g + (size_t)(js * 32 + i) * D_))[op];

    // ---- Phase 0: stage small tensors ----
    float* s_aqf = (float*)s_eat;             // [c*128+d], first 2048 B of the s_eat slab
    if (tid < D_) {
        s_wf[tid]  = wf_g[tid];
        s_bfb[tid] = bfb_g[tid];
        int c = tid >> 5, n = tid & 31;
        int gi = (b * C_ + c0 + c) * N_ + n;
        s_dist[c][n] = dist_g[gi];
        s_mask[c][n] = mask_g[gi];
    }
    {
        s_aqf[tid] = aq_g[(b * C_ + c0 + (tid >> 7)) * D_ + (tid & 127)];
        int i2 = tid + 256;
        s_aqf[i2] = aq_g[(b * C_ + c0 + (i2 >> 7)) * D_ + (i2 & 127)];
    }
    __syncthreads();

    // ---- Phase A: stream + swish-gate atom_neighbor -> s_an (f16 pairs) ----
    {
        const float4* gan = (const float4*)(an_g + (size_t)(b * C_ + c0) * N_ * D_);
        #pragma unroll
        for (int k = 0; k < 16; k++) {
            int ci = k * T_ + tid;                  // float4 chunk index, 4096 total
            float4 v = gan[ci];
            int d4 = ci & 31, n = (ci >> 5) & 31, c = ci >> 10;
            float dist = s_dist[c][n];
            int d0 = d4 << 2;
            float4 wf = *(const float4*)&s_wf[d0];
            float4 bb = *(const float4*)&s_bfb[d0];
            float g0 = swishf(fmaf(dist, wf.x, bb.x));
            float g1 = swishf(fmaf(dist, wf.y, bb.y));
            float g2 = swishf(fmaf(dist, wf.z, bb.z));
            float g3 = swishf(fmaf(dist, wf.w, bb.w));
            u32 o0 = pkrtz(v.x * g0, v.y * g1);
            u32 o1 = pkrtz(v.z * g2, v.w * g3);
            *(uint2*)(s_an + (c * N_ + n) * 136 + d0) = make_uint2(o0, o1);
        }
    }

    // ---- Phase B: q partials — thread (op,js) covers j in [js*32, js*32+32) ----
    {
        float acc0[G_], acc1[G_];
        #pragma unroll
        for (int c = 0; c < G_; c++) { acc0[c] = 0.f; acc1[c] = 0.f; }
        #pragma unroll
        for (int i4 = 0; i4 < 8; i4++) {
            #pragma unroll
            for (int c = 0; c < G_; c++) {
                float4 a4 = *(const float4*)&s_aqf[c * D_ + js * 32 + i4 * 4];
                float2 w0 = wq2[i4 * 4], w1 = wq2[i4 * 4 + 1];
                float2 w2 = wq2[i4 * 4 + 2], w3 = wq2[i4 * 4 + 3];
                acc0[c] = fmaf(a4.x, w0.x, acc0[c]); acc1[c] = fmaf(a4.x, w0.y, acc1[c]);
                acc0[c] = fmaf(a4.y, w1.x, acc0[c]); acc1[c] = fmaf(a4.y, w1.y, acc1[c]);
                acc0[c] = fmaf(a4.z, w2.x, acc0[c]); acc1[c] = fmaf(a4.z, w2.y, acc1[c]);
                acc0[c] = fmaf(a4.w, w3.x, acc0[c]); acc1[c] = fmaf(a4.w, w3.y, acc1[c]);
            }
        }
        float* s_part = (float*)s_ts;   // [js][c][128] scratch, 8 KB
        #pragma unroll
        for (int c = 0; c < G_; c++) {
            *(float2*)&s_part[(js * G_ + c) * D_ + 2 * op] = make_float2(acc0[c], acc1[c]);
        }
    }
    __syncthreads();

    // ---- Phase B2: reduce partials -> s_q (head stride 20) ----
    {
        const float* s_part = (const float*)s_ts;
        #pragma unroll
        for (int r = 0; r < 2; r++) {
            int lin = r * 256 + tid;
            int c = lin >> 7, od = lin & 127;
            float sum = s_part[(0 * G_ + c) * D_ + od] + s_part[(1 * G_ + c) * D_ + od]
                      + s_part[(2 * G_ + c) * D_ + od] + s_part[(3 * G_ + c) * D_ + od];
            s_q[c][(od >> 4) * 20 + (od & 15)] = sum + bq_g[od];
        }
    }
    __syncthreads();

    // ---- Prefetch Wv slice (latency hidden behind C/D/E/F) ----
    float2 wv2[32];
    #pragma unroll
    for (int i = 0; i < 32; i++)
        wv2[i] = ((const float2*)(wv_g + (size_t)(js * 32 + i) * D_))[op];

    // ---- Phase C: t[c,h,j] = 0.25*sum_d' q*Wk, packed f16 pairs into t32 ----
    // thread (h, jb) owns j in {2jb, 2jb+1, 64+2jb, 64+2jb+1}
    // NOTE: no qv[] staging array — q consumed straight from float4 regs
    // (r6's braced-init qv[16] spilled to scratch: +65MB HBM writes).
    {
        u32* t32 = s_ts;                   // [c*8+h][68] u32 (f16 pairs), 8.7 KB
        int h = tid & 7, jb = tid >> 3;    // jb in 0..31
        float wk[4][16];
        #pragma unroll
        for (int jj = 0; jj < 4; jj++) {
            int j = 2 * jb + (jj & 1) + (jj >> 1) * 64;
            const float4* pk = (const float4*)(wk_g + j * D_ + h * 16);
            float4 k0 = pk[0], k1 = pk[1], k2 = pk[2], k3 = pk[3];
            wk[jj][0]  = k0.x; wk[jj][1]  = k0.y; wk[jj][2]  = k0.z; wk[jj][3]  = k0.w;
            wk[jj][4]  = k1.x; wk[jj][5]  = k1.y; wk[jj][6]  = k1.z; wk[jj][7]  = k1.w;
            wk[jj][8]  = k2.x; wk[jj][9]  = k2.y; wk[jj][10] = k2.z; wk[jj][11] = k2.w;
            wk[jj][12] = k3.x; wk[jj][13] = k3.y; wk[jj][14] = k3.z; wk[jj][15] = k3.w;
        }
        #pragma unroll
        for (int c = 0; c < G_; c++) {
            const float4* pq = (const float4*)&s_q[c][h * 20];   // 80B base: 16B aligned
            float4 q0 = pq[0], q1 = pq[1], q2 = pq[2], q3 = pq[3];
            float acc[4];
            #pragma unroll
            for (int jj = 0; jj < 4; jj++) {
                float a = 0.f;
                a = fmaf(q0.x, wk[jj][0],  a);
                a = fmaf(q0.y, wk[jj][1],  a);
                a = fmaf(q0.z, wk[jj][2],  a);
                a = fmaf(q0.w, wk[jj][3],  a);
                a = fmaf(q1.x, wk[jj][4],  a);
                a = fmaf(q1.y, wk[jj][5],  a);
                a = fmaf(q1.z, wk[jj][6],  a);
                a = fmaf(q1.w, wk[jj][7],  a);
                a = fmaf(q2.x, wk[jj][8],  a);
                a = fmaf(q2.y, wk[jj][9],  a);
                a = fmaf(q2.z, wk[jj][10], a);
                a = fmaf(q2.w, wk[jj][11], a);
                a = fmaf(q3.x, wk[jj][12], a);
                a = fmaf(q3.y, wk[jj][13], a);
                a = fmaf(q3.z, wk[jj][14], a);
                a = fmaf(q3.w, wk[jj][15], a);
                acc[jj] = a * 0.25f;
            }
            t32[(c * 8 + h) * 68 + jb]      = pkrtz(acc[0], acc[1]);  // pair jb    (j=2jb,2jb+1)
            t32[(c * 8 + h) * 68 + 32 + jb] = pkrtz(acc[2], acc[3]);  // pair jb+32 (j=64+2jb,..)
        }
    }
    __syncthreads();

    // ---- Phase D: energy via v_dot2_f32_f16, fp32 accumulate ----
    {
        const u32* t32 = s_ts;
        int c = tid >> 6, h = (tid >> 3) & 7, n0 = tid & 7;
        const uint4* trow = (const uint4*)(t32 + (c * 8 + h) * 68);
        float acc[4] = {0.f, 0.f, 0.f, 0.f};
        #pragma unroll
        for (int jc = 0; jc < 16; jc++) {
            uint4 t4 = trow[jc];               // 8 f16 = j 8jc..8jc+7
            #pragma unroll
            for (int r = 0; r < 4; r++) {
                int n = n0 + r * 8;
                uint4 a4 = *(const uint4*)(s_an + (c * N_ + n) * 136 + jc * 8);
                float s = acc[r];
                s = fdot2(a4.x, t4.x, s);
                s = fdot2(a4.y, t4.y, s);
                s = fdot2(a4.z, t4.z, s);
                s = fdot2(a4.w, t4.w, s);
                acc[r] = s;
            }
        }
        #pragma unroll
        for (int r = 0; r < 4; r++) {
            int n = n0 + r * 8;
            float mk = s_mask[c][n];
            s_eat[c][h][n] = acc[r] + (1.0f - mk) * (-1.0e9f);
        }
    }
    __syncthreads();

    // ---- Phase E: softmax; write attn to global; store (am,am) f16 pairs ----
    if (tid < G_ * H_) {
        int c = tid >> 3, h = tid & 7;
        float e[N_];
        float m = -3.0e38f;
        #pragma unroll
        for (int n = 0; n < N_; n++) { e[n] = s_eat[c][h][n]; m = fmaxf(m, e[n]); }
        float sum = 0.f;
        #pragma unroll
        for (int n = 0; n < N_; n++) { float p = __expf(e[n] - m); e[n] = p; sum += p; }
        float inv = 1.0f / sum;
        u32* ampk = (u32*)&s_eat[c][h][0];
        float asum = 0.f;
        size_t off = ((size_t)(b * H_ + h) * C_ + (c0 + c)) * N_;
        #pragma unroll
        for (int n4 = 0; n4 < 8; n4++) {
            float4 w;
            w.x = e[n4 * 4]     * inv;
            w.y = e[n4 * 4 + 1] * inv;
            w.z = e[n4 * 4 + 2] * inv;
            w.w = e[n4 * 4 + 3] * inv;
            *(float4*)(attn_o + off + n4 * 4) = w;
            float am0 = w.x * s_mask[c][n4 * 4];
            float am1 = w.y * s_mask[c][n4 * 4 + 1];
            float am2 = w.z * s_mask[c][n4 * 4 + 2];
            float am3 = w.w * s_mask[c][n4 * 4 + 3];
            asum += am0 + am1 + am2 + am3;
            ampk[n4 * 4]     = pkrtz(am0, am0);
            ampk[n4 * 4 + 1] = pkrtz(am1, am1);
            ampk[n4 * 4 + 2] = pkrtz(am2, am2);
            ampk[n4 * 4 + 3] = pkrtz(am3, am3);
        }
        s_asum[c][h] = asum;
    }
    __syncthreads();

    // ---- Phase F: s[c,h,j] = sum_n am*an via v_pk_fma_f16 (f16x2 acc) ----
    // Output s (f32) goes into this c's slab of s_an: each wave reads only its
    // own c-rows and the write data depends on every read -> safe WAR in-wave;
    // other waves never touch this slab.
    {
        int c = tid >> 6, h = (tid >> 3) & 7, jg = tid & 7;
        const u32* ampk = (const u32*)&s_eat[c][h][0];
        __half2 acc2[8];
        #pragma unroll
        for (int i = 0; i < 8; i++) acc2[i] = __float2half2_rn(0.f);
        #pragma unroll 4
        for (int n = 0; n < N_; n++) {
            u32 am2 = ampk[n];
            const uint4* arow = (const uint4*)(s_an + (c * N_ + n) * 136 + jg * 16);
            uint4 a0 = arow[0], a1 = arow[1];
            acc2[0] = fma2(a0.x, am2, acc2[0]);
            acc2[1] = fma2(a0.y, am2, acc2[1]);
            acc2[2] = fma2(a0.z, am2, acc2[2]);
            acc2[3] = fma2(a0.w, am2, acc2[3]);
            acc2[4] = fma2(a1.x, am2, acc2[4]);
            acc2[5] = fma2(a1.y, am2, acc2[5]);
            acc2[6] = fma2(a1.z, am2, acc2[6]);
            acc2[7] = fma2(a1.w, am2, acc2[7]);
        }
        float* srow = (float*)(s_an + c * (N_ * 136)) + h * 132 + jg * 16;
        #pragma unroll
        for (int p = 0; p < 4; p++) {
            float2 lo = __half22float2(acc2[p * 2]);
            float2 hi = __half22float2(acc2[p * 2 + 1]);
            *(float4*)(srow + p * 4) = make_float4(lo.x, lo.y, hi.x, hi.y);
        }
    }
    __syncthreads();

    // ---- Phase G: ctx partials — thread (op,js), Wv read once per block ----
    {
        int h = op >> 3;                  // od = 2*op -> head = od/16
        float acc0[G_], acc1[G_];
        #pragma unroll
        for (int c = 0; c < G_; c++) { acc0[c] = 0.f; acc1[c] = 0.f; }
        #pragma unroll
        for (int i4 = 0; i4 < 8; i4++) {
            #pragma unroll
            for (int c = 0; c < G_; c++) {
                const float* sc_ = (const float*)(s_an + c * (N_ * 136));
                float4 s4 = *(const float4*)&sc_[h * 132 + js * 32 + i4 * 4];
                float2 w0 = wv2[i4 * 4], w1 = wv2[i4 * 4 + 1];
                float2 w2 = wv2[i4 * 4 + 2], w3 = wv2[i4 * 4 + 3];
                acc0[c] = fmaf(s4.x, w0.x, acc0[c]); acc1[c] = fmaf(s4.x, w0.y, acc1[c]);
                acc0[c] = fmaf(s4.y, w1.x, acc0[c]); acc1[c] = fmaf(s4.y, w1.y, acc1[c]);
                acc0[c] = fmaf(s4.z, w2.x, acc0[c]); acc1[c] = fmaf(s4.z, w2.y, acc1[c]);
                acc0[c] = fmaf(s4.w, w3.x, acc0[c]); acc1[c] = fmaf(s4.w, w3.y, acc1[c]);
            }
        }
        float* s_gp = (float*)s_ts;       // 8 KB scratch, t32 dead after D
        #pragma unroll
        for (int c = 0; c < G_; c++) {
            *(float2*)&s_gp[(js * G_ + c) * D_ + 2 * op] = make_float2(acc0[c], acc1[c]);
        }
    }
    __syncthreads();

    // ---- Phase G2: reduce partials + bias + residual -> ctx ----
    {
        const float* s_gp = (const float*)s_ts;
        #pragma unroll
        for (int r = 0; r < 2; r++) {
            int lin = r * 256 + tid;
            int c = lin >> 7, od = lin & 127;
            int h = od >> 4;
            float sum = s_gp[(0 * G_ + c) * D_ + od] + s_gp[(1 * G_ + c) * D_ + od]
                      + s_gp[(2 * G_ + c) * D_ + od] + s_gp[(3 * G_ + c) * D_ + od];
            float r0 = sum + s_asum[c][h] * bv_g[od] + s_q[c][h * 20 + (od & 15)];
            ctx_o[((size_t)(b * C_ + c0 + c)) * D_ + od] = r0;
        }
    }
}

extern "C" void kernel_launch(void* const* d_in, const int* in_sizes, int n_in,
                              void* d_out, int out_size, void* d_ws, size_t ws_size,
                              hipStream_t stream) {
    const float* aq   = (const float*)d_in[0];
    const float* an   = (const float*)d_in[1];
    const float* dist = (const float*)d_in[2];
    const float* mask = (const float*)d_in[3];
    const float* wq   = (const float*)d_in[4];
    const float* bq   = (const float*)d_in[5];
    const float* wk   = (const float*)d_in[6];
    // d_in[7] = bk: constant over n -> cancels exactly in softmax.
    const float* wv   = (const float*)d_in[8];
    const float* bv   = (const float*)d_in[9];
    const float* wf   = (const float*)d_in[10];
    const float* bfb  = (const float*)d_in[11];

    float* attn_o = (float*)d_out;
    float* ctx_o  = attn_o + (size_t)B_ * H_ * C_ * N_;

    dim3 grid(B_ * C_ / G_), block(T_);
    hipLaunchKernelGGL(la_kernel, grid, block, 0, stream,
                       aq, an, dist, mask, wq, bq, wk, wv, bv, wf, bfb,
                       attn_o, ctx_o);
}

// Round 3
// 424.878 us; speedup vs baseline: 1.0674x; 1.0466x over previous
//
#include <hip/hip_runtime.h>
#include <hip/hip_fp16.h>
#include <cstdint>

// LocalAttention fused kernel, round 8: remove forced wv2 liveness (de-spill v2).
//
// Round-7 post-mortem: WRITE_SIZE byte-identical to r6 (89.9MB = outputs 25MB
// + 65MB == 64B/thread scratch) -> qv wasn't the spill. Real cause: wv2[32]
// (64 VGPRs) force-loaded before Phase C and live across C..F, on top of
// Phase C's wk[4][16]+q+acc (~110 regs) -> ~175 peak > launch_bounds(256,3)
// cap of 170 -> allocator spills 16 dwords/thread. r5 (cap 256) never spilled.
// Fix: load Wv at use inside Phase G (4x float2 per i4 batch; L1/L2-warm,
// 12 waves/CU hide the latency). Peak pressure ~110 -> no spill possible.
// wq2 prefetch kept (clean in r5; overlaps Phase-A HBM stream).
//
// Retained structure:
//  - LDS 52,480 B -> 3 blocks/CU (launch_bounds(256,3))
//  - Phase-F s[c,h,j] (f32) in per-c slab of s_an; s_ts 8,704B time-shared;
//    s_aq overlays s_eat; s_q head stride 20 (bank-spread broadcast reads)
//
// Algebra (exact in real arithmetic):
//   energy[h,n] = sum_j an[n,j] * t[h,j],  t[h,j] = 0.25 * sum_d' q[h,d'] Wk[j,h*16+d']
//     (bk constant over n -> cancels in softmax)
//   ctx[h,d'] = sum_j s[h,j] * Wv[j,h*16+d'] + (sum_n attnm[h,n]) * bv[h,d']
//     with s[h,:] = attnm[h,:] @ an

#define B_ 16
#define C_ 1024
#define N_ 32
#define H_ 8
#define D_ 128
#define G_ 4
#define T_ 256

typedef unsigned short u16;
typedef unsigned int u32;
typedef __fp16 hw2 __attribute__((ext_vector_type(2)));   // matches builtin sigs

__device__ __forceinline__ u32 pkrtz(float a, float b) {
    hw2 r = __builtin_amdgcn_cvt_pkrtz(a, b);
    return __builtin_bit_cast(u32, r);
}
__device__ __forceinline__ float fdot2(u32 a, u32 b, float c) {
#if __has_builtin(__builtin_amdgcn_fdot2)
    return __builtin_amdgcn_fdot2(__builtin_bit_cast(hw2, a),
                                  __builtin_bit_cast(hw2, b), c, false);
#else
    float2 A = __half22float2(__builtin_bit_cast(__half2, a));
    float2 B = __half22float2(__builtin_bit_cast(__half2, b));
    return fmaf(A.y, B.y, fmaf(A.x, B.x, c));
#endif
}
__device__ __forceinline__ __half2 fma2(u32 a, u32 b, __half2 c) {
    return __hfma2(__builtin_bit_cast(__half2, a),
                   __builtin_bit_cast(__half2, b), c);
}
__device__ __forceinline__ float swishf(float x) {
    float s = __builtin_amdgcn_rcpf(1.0f + __expf(-x));
    return x * s;
}

__global__ __launch_bounds__(T_, 3)
void la_kernel(const float* __restrict__ aq_g,  const float* __restrict__ an_g,
               const float* __restrict__ dist_g, const float* __restrict__ mask_g,
               const float* __restrict__ wq_g,  const float* __restrict__ bq_g,
               const float* __restrict__ wk_g,
               const float* __restrict__ wv_g,  const float* __restrict__ bv_g,
               const float* __restrict__ wf_g,  const float* __restrict__ bfb_g,
               float* __restrict__ attn_o, float* __restrict__ ctx_o)
{
    // LDS: 34816(s_an) + 8704(s_ts) + 2560(s_q) + 4224(s_eat) + 512+512+128+512+512
    //    = 52,480 B  -> 3 blocks/CU
    __shared__ __align__(16) u16   s_an[G_ * N_ * 136];   // gated neighbors f16; per-c f32 s-slab after F
    __shared__ __align__(16) u32   s_ts[G_ * H_ * 68];    // B-partials(f32) / t32(f16 pairs) / G-partials(f32)
    __shared__ __align__(16) float s_q[G_][H_ * 20];      // projected query (unscaled), head stride 20
    __shared__ __align__(16) float s_eat[G_][H_][33];     // aq staging (ph0..B) -> energy f32 (D/E) -> am pairs (F)
    __shared__ float s_dist[G_][N_];
    __shared__ float s_mask[G_][N_];
    __shared__ float s_asum[G_][H_];
    __shared__ __align__(16) float s_wf[D_];
    __shared__ __align__(16) float s_bfb[D_];

    const int tid = threadIdx.x;
    const int b   = blockIdx.x >> 8;          // 256 c-groups per b
    const int c0  = (blockIdx.x & 255) << 2;  // G_=4 c's per block

    const int op = tid & 63;                  // output-pair index (od = 2*op)
    const int js = tid >> 6;                  // j-slice index (rows js*32 .. js*32+31)

    // ---- Prefetch Wq slice into registers (overlaps Phase A an-stream) ----
    float2 wq2[32];
    #pragma unroll
    for (int i = 0; i < 32; i++)
        wq2[i] = ((const float2*)(wq_g + (size_t)(js * 32 + i) * D_))[op];

    // ---- Phase 0: stage small tensors ----
    float* s_aqf = (float*)s_eat;             // [c*128+d], first 2048 B of the s_eat slab
    if (tid < D_) {
        s_wf[tid]  = wf_g[tid];
        s_bfb[tid] = bfb_g[tid];
        int c = tid >> 5, n = tid & 31;
        int gi = (b * C_ + c0 + c) * N_ + n;
        s_dist[c][n] = dist_g[gi];
        s_mask[c][n] = mask_g[gi];
    }
    {
        s_aqf[tid] = aq_g[(b * C_ + c0 + (tid >> 7)) * D_ + (tid & 127)];
        int i2 = tid + 256;
        s_aqf[i2] = aq_g[(b * C_ + c0 + (i2 >> 7)) * D_ + (i2 & 127)];
    }
    __syncthreads();

    // ---- Phase A: stream + swish-gate atom_neighbor -> s_an (f16 pairs) ----
    {
        const float4* gan = (const float4*)(an_g + (size_t)(b * C_ + c0) * N_ * D_);
        #pragma unroll
        for (int k = 0; k < 16; k++) {
            int ci = k * T_ + tid;                  // float4 chunk index, 4096 total
            float4 v = gan[ci];
            int d4 = ci & 31, n = (ci >> 5) & 31, c = ci >> 10;
            float dist = s_dist[c][n];
            int d0 = d4 << 2;
            float4 wf = *(const float4*)&s_wf[d0];
            float4 bb = *(const float4*)&s_bfb[d0];
            float g0 = swishf(fmaf(dist, wf.x, bb.x));
            float g1 = swishf(fmaf(dist, wf.y, bb.y));
            float g2 = swishf(fmaf(dist, wf.z, bb.z));
            float g3 = swishf(fmaf(dist, wf.w, bb.w));
            u32 o0 = pkrtz(v.x * g0, v.y * g1);
            u32 o1 = pkrtz(v.z * g2, v.w * g3);
            *(uint2*)(s_an + (c * N_ + n) * 136 + d0) = make_uint2(o0, o1);
        }
    }

    // ---- Phase B: q partials — thread (op,js) covers j in [js*32, js*32+32) ----
    {
        float acc0[G_], acc1[G_];
        #pragma unroll
        for (int c = 0; c < G_; c++) { acc0[c] = 0.f; acc1[c] = 0.f; }
        #pragma unroll
        for (int i4 = 0; i4 < 8; i4++) {
            #pragma unroll
            for (int c = 0; c < G_; c++) {
                float4 a4 = *(const float4*)&s_aqf[c * D_ + js * 32 + i4 * 4];
                float2 w0 = wq2[i4 * 4], w1 = wq2[i4 * 4 + 1];
                float2 w2 = wq2[i4 * 4 + 2], w3 = wq2[i4 * 4 + 3];
                acc0[c] = fmaf(a4.x, w0.x, acc0[c]); acc1[c] = fmaf(a4.x, w0.y, acc1[c]);
                acc0[c] = fmaf(a4.y, w1.x, acc0[c]); acc1[c] = fmaf(a4.y, w1.y, acc1[c]);
                acc0[c] = fmaf(a4.z, w2.x, acc0[c]); acc1[c] = fmaf(a4.z, w2.y, acc1[c]);
                acc0[c] = fmaf(a4.w, w3.x, acc0[c]); acc1[c] = fmaf(a4.w, w3.y, acc1[c]);
            }
        }
        float* s_part = (float*)s_ts;   // [js][c][128] scratch, 8 KB
        #pragma unroll
        for (int c = 0; c < G_; c++) {
            *(float2*)&s_part[(js * G_ + c) * D_ + 2 * op] = make_float2(acc0[c], acc1[c]);
        }
    }
    __syncthreads();

    // ---- Phase B2: reduce partials -> s_q (head stride 20) ----
    {
        const float* s_part = (const float*)s_ts;
        #pragma unroll
        for (int r = 0; r < 2; r++) {
            int lin = r * 256 + tid;
            int c = lin >> 7, od = lin & 127;
            float sum = s_part[(0 * G_ + c) * D_ + od] + s_part[(1 * G_ + c) * D_ + od]
                      + s_part[(2 * G_ + c) * D_ + od] + s_part[(3 * G_ + c) * D_ + od];
            s_q[c][(od >> 4) * 20 + (od & 15)] = sum + bq_g[od];
        }
    }
    __syncthreads();

    // ---- Phase C: t[c,h,j] = 0.25*sum_d' q*Wk, packed f16 pairs into t32 ----
    // thread (h, jb) owns j in {2jb, 2jb+1, 64+2jb, 64+2jb+1}
    {
        u32* t32 = s_ts;                   // [c*8+h][68] u32 (f16 pairs), 8.7 KB
        int h = tid & 7, jb = tid >> 3;    // jb in 0..31
        float wk[4][16];
        #pragma unroll
        for (int jj = 0; jj < 4; jj++) {
            int j = 2 * jb + (jj & 1) + (jj >> 1) * 64;
            const float4* pk = (const float4*)(wk_g + j * D_ + h * 16);
            float4 k0 = pk[0], k1 = pk[1], k2 = pk[2], k3 = pk[3];
            wk[jj][0]  = k0.x; wk[jj][1]  = k0.y; wk[jj][2]  = k0.z; wk[jj][3]  = k0.w;
            wk[jj][4]  = k1.x; wk[jj][5]  = k1.y; wk[jj][6]  = k1.z; wk[jj][7]  = k1.w;
            wk[jj][8]  = k2.x; wk[jj][9]  = k2.y; wk[jj][10] = k2.z; wk[jj][11] = k2.w;
            wk[jj][12] = k3.x; wk[jj][13] = k3.y; wk[jj][14] = k3.z; wk[jj][15] = k3.w;
        }
        #pragma unroll
        for (int c = 0; c < G_; c++) {
            const float4* pq = (const float4*)&s_q[c][h * 20];   // 80B base: 16B aligned
            float4 q0 = pq[0], q1 = pq[1], q2 = pq[2], q3 = pq[3];
            float acc[4];
            #pragma unroll
            for (int jj = 0; jj < 4; jj++) {
                float a = 0.f;
                a = fmaf(q0.x, wk[jj][0],  a);
                a = fmaf(q0.y, wk[jj][1],  a);
                a = fmaf(q0.z, wk[jj][2],  a);
                a = fmaf(q0.w, wk[jj][3],  a);
                a = fmaf(q1.x, wk[jj][4],  a);
                a = fmaf(q1.y, wk[jj][5],  a);
                a = fmaf(q1.z, wk[jj][6],  a);
                a = fmaf(q1.w, wk[jj][7],  a);
                a = fmaf(q2.x, wk[jj][8],  a);
                a = fmaf(q2.y, wk[jj][9],  a);
                a = fmaf(q2.z, wk[jj][10], a);
                a = fmaf(q2.w, wk[jj][11], a);
                a = fmaf(q3.x, wk[jj][12], a);
                a = fmaf(q3.y, wk[jj][13], a);
                a = fmaf(q3.z, wk[jj][14], a);
                a = fmaf(q3.w, wk[jj][15], a);
                acc[jj] = a * 0.25f;
            }
            t32[(c * 8 + h) * 68 + jb]      = pkrtz(acc[0], acc[1]);  // pair jb    (j=2jb,2jb+1)
            t32[(c * 8 + h) * 68 + 32 + jb] = pkrtz(acc[2], acc[3]);  // pair jb+32 (j=64+2jb,..)
        }
    }
    __syncthreads();

    // ---- Phase D: energy via v_dot2_f32_f16, fp32 accumulate ----
    {
        const u32* t32 = s_ts;
        int c = tid >> 6, h = (tid >> 3) & 7, n0 = tid & 7;
        const uint4* trow = (const uint4*)(t32 + (c * 8 + h) * 68);
        float acc[4] = {0.f, 0.f, 0.f, 0.f};
        #pragma unroll
        for (int jc = 0; jc < 16; jc++) {
            uint4 t4 = trow[jc];               // 8 f16 = j 8jc..8jc+7
            #pragma unroll
            for (int r = 0; r < 4; r++) {
                int n = n0 + r * 8;
                uint4 a4 = *(const uint4*)(s_an + (c * N_ + n) * 136 + jc * 8);
                float s = acc[r];
                s = fdot2(a4.x, t4.x, s);
                s = fdot2(a4.y, t4.y, s);
                s = fdot2(a4.z, t4.z, s);
                s = fdot2(a4.w, t4.w, s);
                acc[r] = s;
            }
        }
        #pragma unroll
        for (int r = 0; r < 4; r++) {
            int n = n0 + r * 8;
            float mk = s_mask[c][n];
            s_eat[c][h][n] = acc[r] + (1.0f - mk) * (-1.0e9f);
        }
    }
    __syncthreads();

    // ---- Phase E: softmax; write attn to global; store (am,am) f16 pairs ----
    if (tid < G_ * H_) {
        int c = tid >> 3, h = tid & 7;
        float e[N_];
        float m = -3.0e38f;
        #pragma unroll
        for (int n = 0; n < N_; n++) { e[n] = s_eat[c][h][n]; m = fmaxf(m, e[n]); }
        float sum = 0.f;
        #pragma unroll
        for (int n = 0; n < N_; n++) { float p = __expf(e[n] - m); e[n] = p; sum += p; }
        float inv = 1.0f / sum;
        u32* ampk = (u32*)&s_eat[c][h][0];
        float asum = 0.f;
        size_t off = ((size_t)(b * H_ + h) * C_ + (c0 + c)) * N_;
        #pragma unroll
        for (int n4 = 0; n4 < 8; n4++) {
            float4 w;
            w.x = e[n4 * 4]     * inv;
            w.y = e[n4 * 4 + 1] * inv;
            w.z = e[n4 * 4 + 2] * inv;
            w.w = e[n4 * 4 + 3] * inv;
            *(float4*)(attn_o + off + n4 * 4) = w;
            float am0 = w.x * s_mask[c][n4 * 4];
            float am1 = w.y * s_mask[c][n4 * 4 + 1];
            float am2 = w.z * s_mask[c][n4 * 4 + 2];
            float am3 = w.w * s_mask[c][n4 * 4 + 3];
            asum += am0 + am1 + am2 + am3;
            ampk[n4 * 4]     = pkrtz(am0, am0);
            ampk[n4 * 4 + 1] = pkrtz(am1, am1);
            ampk[n4 * 4 + 2] = pkrtz(am2, am2);
            ampk[n4 * 4 + 3] = pkrtz(am3, am3);
        }
        s_asum[c][h] = asum;
    }
    __syncthreads();

    // ---- Phase F: s[c,h,j] = sum_n am*an via v_pk_fma_f16 (f16x2 acc) ----
    // Output s (f32) goes into this c's slab of s_an: each wave reads only its
    // own c-rows and the write data depends on every read -> safe WAR in-wave;
    // other waves never touch this slab.
    {
        int c = tid >> 6, h = (tid >> 3) & 7, jg = tid & 7;
        const u32* ampk = (const u32*)&s_eat[c][h][0];
        __half2 acc2[8];
        #pragma unroll
        for (int i = 0; i < 8; i++) acc2[i] = __float2half2_rn(0.f);
        #pragma unroll 4
        for (int n = 0; n < N_; n++) {
            u32 am2 = ampk[n];
            const uint4* arow = (const uint4*)(s_an + (c * N_ + n) * 136 + jg * 16);
            uint4 a0 = arow[0], a1 = arow[1];
            acc2[0] = fma2(a0.x, am2, acc2[0]);
            acc2[1] = fma2(a0.y, am2, acc2[1]);
            acc2[2] = fma2(a0.z, am2, acc2[2]);
            acc2[3] = fma2(a0.w, am2, acc2[3]);
            acc2[4] = fma2(a1.x, am2, acc2[4]);
            acc2[5] = fma2(a1.y, am2, acc2[5]);
            acc2[6] = fma2(a1.z, am2, acc2[6]);
            acc2[7] = fma2(a1.w, am2, acc2[7]);
        }
        float* srow = (float*)(s_an + c * (N_ * 136)) + h * 132 + jg * 16;
        #pragma unroll
        for (int p = 0; p < 4; p++) {
            float2 lo = __half22float2(acc2[p * 2]);
            float2 hi = __half22float2(acc2[p * 2 + 1]);
            *(float4*)(srow + p * 4) = make_float4(lo.x, lo.y, hi.x, hi.y);
        }
    }
    __syncthreads();

    // ---- Phase G: ctx partials — Wv loaded AT USE (no live-across-phases
    // array; r6/r7 held wv2[32]=64 VGPRs live across C..F -> spill under the
    // 170-reg cap of launch_bounds(256,3)). Wv is L1/L2-warm for all but the
    // first blocks; 12 waves/CU hide the hit latency. ----
    {
        int h = op >> 3;                  // od = 2*op -> head = od/16
        float acc0[G_], acc1[G_];
        #pragma unroll
        for (int c = 0; c < G_; c++) { acc0[c] = 0.f; acc1[c] = 0.f; }
        #pragma unroll
        for (int i4 = 0; i4 < 8; i4++) {
            float2 w0 = ((const float2*)(wv_g + (size_t)(js * 32 + i4 * 4 + 0) * D_))[op];
            float2 w1 = ((const float2*)(wv_g + (size_t)(js * 32 + i4 * 4 + 1) * D_))[op];
            float2 w2 = ((const float2*)(wv_g + (size_t)(js * 32 + i4 * 4 + 2) * D_))[op];
            float2 w3 = ((const float2*)(wv_g + (size_t)(js * 32 + i4 * 4 + 3) * D_))[op];
            #pragma unroll
            for (int c = 0; c < G_; c++) {
                const float* sc_ = (const float*)(s_an + c * (N_ * 136));
                float4 s4 = *(const float4*)&sc_[h * 132 + js * 32 + i4 * 4];
                acc0[c] = fmaf(s4.x, w0.x, acc0[c]); acc1[c] = fmaf(s4.x, w0.y, acc1[c]);
                acc0[c] = fmaf(s4.y, w1.x, acc0[c]); acc1[c] = fmaf(s4.y, w1.y, acc1[c]);
                acc0[c] = fmaf(s4.z, w2.x, acc0[c]); acc1[c] = fmaf(s4.z, w2.y, acc1[c]);
                acc0[c] = fmaf(s4.w, w3.x, acc0[c]); acc1[c] = fmaf(s4.w, w3.y, acc1[c]);
            }
        }
        float* s_gp = (float*)s_ts;       // 8 KB scratch, t32 dead after D
        #pragma unroll
        for (int c = 0; c < G_; c++) {
            *(float2*)&s_gp[(js * G_ + c) * D_ + 2 * op] = make_float2(acc0[c], acc1[c]);
        }
    }
    __syncthreads();

    // ---- Phase G2: reduce partials + bias + residual -> ctx ----
    {
        const float* s_gp = (const float*)s_ts;
        #pragma unroll
        for (int r = 0; r < 2; r++) {
            int lin = r * 256 + tid;
            int c = lin >> 7, od = lin & 127;
            int h = od >> 4;
            float sum = s_gp[(0 * G_ + c) * D_ + od] + s_gp[(1 * G_ + c) * D_ + od]
                      + s_gp[(2 * G_ + c) * D_ + od] + s_gp[(3 * G_ + c) * D_ + od];
            float r0 = sum + s_asum[c][h] * bv_g[od] + s_q[c][h * 20 + (od & 15)];
            ctx_o[((size_t)(b * C_ + c0 + c)) * D_ + od] = r0;
        }
    }
}

extern "C" void kernel_launch(void* const* d_in, const int* in_sizes, int n_in,
                              void* d_out, int out_size, void* d_ws, size_t ws_size,
                              hipStream_t stream) {
    const float* aq   = (const float*)d_in[0];
    const float* an   = (const float*)d_in[1];
    const float* dist = (const float*)d_in[2];
    const float* mask = (const float*)d_in[3];
    const float* wq   = (const float*)d_in[4];
    const float* bq   = (const float*)d_in[5];
    const float* wk   = (const float*)d_in[6];
    // d_in[7] = bk: constant over n -> cancels exactly in softmax.
    const float* wv   = (const float*)d_in[8];
    const float* bv   = (const float*)d_in[9];
    const float* wf   = (const float*)d_in[10];
    const float* bfb  = (const float*)d_in[11];

    float* attn_o = (float*)d_out;
    float* ctx_o  = attn_o + (size_t)B_ * H_ * C_ * N_;

    dim3 grid(B_ * C_ / G_), block(T_);
    hipLaunchKernelGGL(la_kernel, grid, block, 0, stream,
                       aq, an, dist, mask, wq, bq, wk, wv, bv, wf, bfb,
                       attn_o, ctx_o);
}